// Round 9
// baseline (416.735 us; speedup 1.0000x reference)
//
#include <hip/hip_runtime.h>
#include <hip/hip_bf16.h>
#include <stdint.h>

typedef __bf16 bf16x8 __attribute__((ext_vector_type(8)));
typedef float f32x4 __attribute__((ext_vector_type(4)));
typedef unsigned short u16x4 __attribute__((ext_vector_type(4)));

__device__ __forceinline__ unsigned short f2bf(float f) {
    union { float f; uint32_t u; } v; v.f = f;
    uint32_t u = v.u;
    return (unsigned short)((u + 0x7fffu + ((u >> 16) & 1u)) >> 16);
}

__device__ __forceinline__ float bf2f(unsigned short b) {
    union { uint32_t u; float f; } v; v.u = ((uint32_t)b) << 16;
    return v.f;
}

// ---- prep: f32 -> bf16 feature conversion (x4); tail zeroes the pad row ----
__global__ __launch_bounds__(256) void prep_x(const f32x4* __restrict__ x,
                                              u16x4* __restrict__ xb, int n4, int n4tot) {
    int t = blockIdx.x * 256 + threadIdx.x;
    if (t < n4) {
        f32x4 v = x[t];
        u16x4 o;
        o.x = f2bf(v.x); o.y = f2bf(v.y); o.z = f2bf(v.z); o.w = f2bf(v.w);
        xb[t] = o;
    } else if (t < n4tot) {
        u16x4 z = {0, 0, 0, 0};
        xb[t] = z;                       // zero row at index N (masked-gather target)
    }
}

// ---- zero one 64-ch row (pad row of the hidden buffer) ----
__global__ void zero_row(unsigned short* __restrict__ p, long off) {
    p[off + threadIdx.x] = 0;
}

// ---- prep: W[k][ci][co] f32 -> FRAGMENT-ORDERED Wf[k][4096] bf16 ----
// u16 index = (ct*2+h)*512 + l*8 + j  <->  W[ci][co], ci = h*32+(l>>4)*8+j,
// co = ct*16+(l&15). LDS reads become lane-linear (base + lane*16B):
// bank-conflict-free, and staging is a plain linear copy.
__global__ __launch_bounds__(256) void prep_w(const float* __restrict__ W,
                                              unsigned short* __restrict__ Wf) {
    int k = blockIdx.x;
    unsigned short* Wfk = Wf + (size_t)k * 4096;
    const float* Wk = W + (size_t)k * 4096;
    for (int idx = threadIdx.x; idx < 4096; idx += 256) {
        int j   = idx & 7;
        int l   = (idx >> 3) & 63;
        int c2h = idx >> 9;               // ct*2 + h
        int ct  = c2h >> 1, h = c2h & 1;
        int ci  = h * 32 + (l >> 4) * 8 + j;
        int co  = ct * 16 + (l & 15);
        Wfk[idx] = f2bf(Wk[ci * 64 + co]);
    }
}

// ---- detect mask element width: 0=int32, 1=bytes(bool), 2=float32 ----
__global__ void detect_mask(const unsigned int* __restrict__ m, int* __restrict__ flag) {
    __shared__ int s_not_int, s_not_f32;
    if (threadIdx.x == 0) { s_not_int = 0; s_not_f32 = 0; }
    __syncthreads();
    unsigned int w = m[threadIdx.x];          // first 4KB: safe for all widths
    if (w > 1u) s_not_int = 1;                // benign race
    if (w != 0u && w != 0x3f800000u) s_not_f32 = 1;
    __syncthreads();
    if (threadIdx.x == 0) *flag = s_not_int ? (s_not_f32 ? 1 : 2) : 0;
}

// ---- asm 16B gather load (async; counted vmcnt domain) ----
template <int IOFF>
__device__ __forceinline__ bf16x8 gl16(const unsigned short* base, unsigned voff) {
    bf16x8 r;
    asm volatile("global_load_dwordx4 %0, %1, %2 offset:%c3"
                 : "=v"(r) : "v"(voff), "s"(base), "i"(IOFF));
    return r;
}

struct Slot { bf16x8 f[8]; };   // [at*2 + half]: 4 row-tiles x 2 k-halves

// counted wait tying the slot registers: consuming MFMAs can't be hoisted above.
template <int NW>
__device__ __forceinline__ void waitv(Slot& s) {
    asm volatile("s_waitcnt vmcnt(%c8)"
                 : "+v"(s.f[0]), "+v"(s.f[1]), "+v"(s.f[2]), "+v"(s.f[3]),
                   "+v"(s.f[4]), "+v"(s.f[5]), "+v"(s.f[6]), "+v"(s.f[7])
                 : "i"(NW));
    __builtin_amdgcn_sched_barrier(0);
}

__device__ __forceinline__ void gload_lds16(const unsigned short* g, unsigned short* l) {
    __builtin_amdgcn_global_load_lds(
        (const __attribute__((address_space(1))) void*)(const void*)g,
        (__attribute__((address_space(3))) void*)(void*)l, 16, 0, 0);
}

// ---- main sparse conv ----
// 4 waves x 64 rows = 256 rows/block, mfma 16x16x32, 4 row-tiles per wave.
// A gathered straight into fragments; W staged in LDS (fragment-ordered,
// lane-linear reads) double-buffered in 2-slice phases (32,768B LDS).
// Counted vmcnt keeps gathers in flight; bpermuted gather addresses are
// prefetched one step ahead (bpr pipeline); non-temporal stores protect L2.
// MODE 0: out = bf16 relu(acc + bias)   (hidden layer)
// MODE 1: out = f32  acc + bias + bf2f(residb) (final layer)
template <int MODE>
__global__ __launch_bounds__(256, 2) void conv_mfma(
    const unsigned short* __restrict__ xb,   // [N+1][64] bf16 (row N = zeros)
    const int* __restrict__ nbr,             // [N][K]
    const void* __restrict__ maskp,
    const int* __restrict__ flagp,
    const unsigned short* __restrict__ Wf,   // [27][4096] bf16 fragment-ordered
    const float* __restrict__ bias,          // [64]
    const unsigned short* __restrict__ residb, // [N][64] bf16 (MODE 1: = xb)
    void* __restrict__ outp,
    int N, int K)
{
    __shared__ unsigned short Wlds[16384];   // 2 bufs x 2 slices x 4096 = 32,768B

    const int tid = threadIdx.x;
    const int wv  = tid >> 6;
    const int l   = tid & 63;
    const int lr  = l & 15;          // fragment row/col
    const int lg  = l >> 4;          // k-chunk 0..3
    const int wavebase = blockIdx.x * 256 + wv * 64;

    // each lane owns exactly one row's neighbor offsets
    const int myrow = wavebase + l;
    const int mr = myrow < N ? myrow : N - 1;

    // ---- mask bits (uniform branch on detected dtype; streaming nt loads) ----
    unsigned mbits = 0;
    {
        const int flag = *flagp;
        long moff = (long)mr * K;
        if (flag == 1) {
            const unsigned char* mp = (const unsigned char*)maskp + moff;
#pragma unroll
            for (int k = 0; k < 27; ++k)
                mbits |= (__builtin_nontemporal_load(mp + k) ? 1u : 0u) << k;
        } else if (flag == 0) {
            const int* mp = (const int*)maskp + moff;
#pragma unroll
            for (int k = 0; k < 27; ++k)
                mbits |= (__builtin_nontemporal_load(mp + k) ? 1u : 0u) << k;
        } else {
            const float* mp = (const float*)maskp + moff;
#pragma unroll
            for (int k = 0; k < 27; ++k)
                mbits |= ((__builtin_nontemporal_load(mp + k) != 0.f) ? 1u : 0u) << k;
        }
    }

    // ---- per-k byte offsets for my row (masked -> zero row N) ----
    unsigned o[27];
    {
        const int* nrow = nbr + (long)mr * K;
#pragma unroll
        for (int k = 0; k < 27; ++k) {
            int nv = __builtin_nontemporal_load(nrow + k);
            unsigned g = ((mbits >> k) & 1u) ? (unsigned)nv : (unsigned)N;
            o[k] = g * 128u;
        }
    }

    // owner-lane bpermute addresses for the 4 row-tiles
    const int bpa0 = (0 * 16 + lr) * 4;
    const int bpa1 = (1 * 16 + lr) * 4;
    const int bpa2 = (2 * 16 + lr) * 4;
    const int bpa3 = (3 * 16 + lr) * 4;
    const unsigned chk = (unsigned)(lg << 4);    // chunk byte offset within 64B half

    f32x4 acc[4][4] = {};
    Slot pipe[2];
    bf16x8 Bf[8];
    unsigned bpr[2][4];

// stage 2 k-slices (16KB) for phase P into buffer P&1.
// dst is WAVE-UNIFORM (wv-based); src is per-lane (16B-contiguous).
#define STAGE(P) do { \
    const unsigned short* _src = Wf + (size_t)(P) * 8192 + wv * 2048 + (l << 3); \
    unsigned short* _dst = &Wlds[((P) & 1) * 8192 + wv * 2048]; \
    _Pragma("unroll") \
    for (int _s = 0; _s < 4; ++_s) \
        gload_lds16(_src + _s * 512, _dst + _s * 512); \
    asm volatile("" ::: "memory"); \
} while (0)

// stage ONE k-slice (8KB): first half of phase P's region
#define STAGE1(P) do { \
    const unsigned short* _src = Wf + (size_t)(P) * 8192 + wv * 1024 + (l << 3); \
    unsigned short* _dst = &Wlds[((P) & 1) * 8192 + wv * 1024]; \
    _Pragma("unroll") \
    for (int _s = 0; _s < 2; ++_s) \
        gload_lds16(_src + _s * 512, _dst + _s * 512); \
    asm volatile("" ::: "memory"); \
} while (0)

// prefetch the 4 bpermuted gather addresses for step J (lgkm latency hidden)
#define GPERM(J) do { if ((J) <= 26) { \
    bpr[(J) & 1][0] = (unsigned)__builtin_amdgcn_ds_bpermute(bpa0, (int)o[(J)]) + chk; \
    bpr[(J) & 1][1] = (unsigned)__builtin_amdgcn_ds_bpermute(bpa1, (int)o[(J)]) + chk; \
    bpr[(J) & 1][2] = (unsigned)__builtin_amdgcn_ds_bpermute(bpa2, (int)o[(J)]) + chk; \
    bpr[(J) & 1][3] = (unsigned)__builtin_amdgcn_ds_bpermute(bpa3, (int)o[(J)]) + chk; \
} } while (0)

#define GISSUE(J) do { \
    Slot& _s = pipe[(J) & 1]; \
    _s.f[0] = gl16<0 >(xb, bpr[(J) & 1][0]); _s.f[1] = gl16<64>(xb, bpr[(J) & 1][0]); \
    _s.f[2] = gl16<0 >(xb, bpr[(J) & 1][1]); _s.f[3] = gl16<64>(xb, bpr[(J) & 1][1]); \
    _s.f[4] = gl16<0 >(xb, bpr[(J) & 1][2]); _s.f[5] = gl16<64>(xb, bpr[(J) & 1][2]); \
    _s.f[6] = gl16<0 >(xb, bpr[(J) & 1][3]); _s.f[7] = gl16<64>(xb, bpr[(J) & 1][3]); \
} while (0)

// lane-linear fragment read: buf=(J>>1)&1, slice=J&1; conflict-free
#define BLOAD(J) do { \
    const unsigned short* _wl = &Wlds[(((J) >> 1) & 1) * 8192 + ((J) & 1) * 4096]; \
    _Pragma("unroll") \
    for (int _c = 0; _c < 8; ++_c) \
        Bf[_c] = *(const bf16x8*)(_wl + _c * 512 + l * 8); \
} while (0)

#define MFMA16(J) do { \
    Slot& _s = pipe[(J) & 1]; \
    __builtin_amdgcn_s_setprio(1); \
    _Pragma("unroll") \
    for (int ct = 0; ct < 4; ++ct) { \
        _Pragma("unroll") \
        for (int at = 0; at < 4; ++at) { \
            acc[at][ct] = __builtin_amdgcn_mfma_f32_16x16x32_bf16(_s.f[at * 2],     Bf[ct * 2],     acc[at][ct], 0, 0, 0); \
            acc[at][ct] = __builtin_amdgcn_mfma_f32_16x16x32_bf16(_s.f[at * 2 + 1], Bf[ct * 2 + 1], acc[at][ct], 0, 0, 0); \
        } \
    } \
    __builtin_amdgcn_s_setprio(0); \
} while (0)

#define FENCE(NW) do { \
    asm volatile("s_waitcnt vmcnt(%c0)" :: "i"(NW) : "memory"); \
    __builtin_amdgcn_sched_barrier(0); \
    __builtin_amdgcn_s_barrier(); \
    __builtin_amdgcn_sched_barrier(0); \
} while (0)

#define STEP(J, NW) do { BLOAD(J); waitv<NW>(pipe[(J) & 1]); MFMA16(J); } while (0)

// one steady-state phase: stage next buffer, 2 compute steps, 2 gather issues
#define PHASE(PH1, K0) do { \
    STAGE(PH1); \
    STEP(K0, 12);       GISSUE((K0) + 2); GPERM((K0) + 4); \
    STEP((K0) + 1, 12); GISSUE((K0) + 3); GPERM((K0) + 5); \
    FENCE(16); \
} while (0)

    // ---- prologue: stage phase 0, start 2 gather sets, prime perms ----
    STAGE(0);
    GPERM(0); GPERM(1);
    GISSUE(0); GISSUE(1);
    GPERM(2); GPERM(3);
    asm volatile("s_waitcnt vmcnt(16)" ::: "memory");   // STAGE(0) retired; G0,G1 fly
    __builtin_amdgcn_sched_barrier(0);
    __builtin_amdgcn_s_barrier();
    __builtin_amdgcn_sched_barrier(0);

    PHASE(1, 0);   PHASE(2, 2);   PHASE(3, 4);   PHASE(4, 6);
    PHASE(5, 8);   PHASE(6, 10);  PHASE(7, 12);  PHASE(8, 14);
    PHASE(9, 16);  PHASE(10, 18); PHASE(11, 20); PHASE(12, 22);
    // phase 13 (k 24,25; buf 1; stages only slice 26)
    STAGE1(13);
    STEP(24, 10); GISSUE(26);
    STEP(25, 10);
    FENCE(8);
    // tail (k 26; buf 1 slice 0)
    STEP(26, 0);

    // ---- epilogue: D col = ct*16 + lr, row = wavebase + at*16 + lg*4 + rg ----
    // non-temporal stores: don't evict the gather working set from L2
#pragma unroll
    for (int at = 0; at < 4; ++at) {
#pragma unroll
        for (int ct = 0; ct < 4; ++ct) {
            int col = ct * 16 + lr;
            float bv = bias[col];
#pragma unroll
            for (int rg = 0; rg < 4; ++rg) {
                int row = wavebase + at * 16 + lg * 4 + rg;
                if (row < N) {
                    long oo = (long)row * 64 + col;
                    float v = acc[at][ct][rg] + bv;
                    if (MODE == 0) {
                        __builtin_nontemporal_store(f2bf(v > 0.f ? v : 0.f),
                                                    (unsigned short*)outp + oo);
                    } else {
                        unsigned short rb = __builtin_nontemporal_load(residb + oo);
                        __builtin_nontemporal_store(v + bf2f(rb), (float*)outp + oo);
                    }
                }
            }
        }
    }

#undef STAGE
#undef STAGE1
#undef GPERM
#undef GISSUE
#undef BLOAD
#undef MFMA16
#undef FENCE
#undef STEP
#undef PHASE
}

static inline size_t align256(size_t x) { return (x + 255) & ~(size_t)255; }

extern "C" void kernel_launch(void* const* d_in, const int* in_sizes, int n_in,
                              void* d_out, int out_size, void* d_ws, size_t ws_size,
                              hipStream_t stream) {
    const float* x    = (const float*)d_in[0];
    const int*   nbr  = (const int*)d_in[1];
    const void*  mask = d_in[2];
    const float* W0   = (const float*)d_in[3];
    const float* b0   = (const float*)d_in[4];
    const float* W1   = (const float*)d_in[5];
    const float* b1   = (const float*)d_in[6];

    const int NC = in_sizes[0];      // N*64
    const int N  = NC / 64;
    const int K  = in_sizes[1] / N;  // 27

    char* ws = (char*)d_ws;
    size_t xb_bytes = (size_t)(NC + 64) * 2;   // +1 zero row
    size_t wt_bytes = (size_t)28 * 4096 * 2;   // fragment-ordered (27 used)
    size_t xb_off   = 0;
    size_t hb_off   = xb_off + align256(xb_bytes);
    size_t wt0_off  = hb_off + align256(xb_bytes);
    size_t wt1_off  = wt0_off + align256(wt_bytes);
    size_t flag_off = wt1_off + align256(wt_bytes);

    unsigned short* xb  = (unsigned short*)(ws + xb_off);
    unsigned short* hb  = (unsigned short*)(ws + hb_off);
    unsigned short* wf0 = (unsigned short*)(ws + wt0_off);
    unsigned short* wf1 = (unsigned short*)(ws + wt1_off);
    int* flag           = (int*)(ws + flag_off);

    int n4 = NC / 4;
    int n4tot = n4 + 16;             // + zero pad row (16 u16x4 = 64 ch)
    prep_x<<<(n4tot + 255) / 256, 256, 0, stream>>>((const f32x4*)x, (u16x4*)xb, n4, n4tot);
    zero_row<<<1, 64, 0, stream>>>(hb, (long)NC);
    prep_w<<<27, 256, 0, stream>>>(W0, wf0);
    prep_w<<<27, 256, 0, stream>>>(W1, wf1);
    detect_mask<<<1, 1024, 0, stream>>>((const unsigned int*)mask, flag);

    int nblocks = (N + 255) / 256;
    conv_mfma<0><<<nblocks, 256, 0, stream>>>(xb, nbr, mask, flag, wf0, b0, nullptr, hb, N, K);
    conv_mfma<1><<<nblocks, 256, 0, stream>>>(hb, nbr, mask, flag, wf1, b1, xb, d_out, N, K);
}

// Round 10
// 331.866 us; speedup vs baseline: 1.2557x; 1.2557x over previous
//
#include <hip/hip_runtime.h>
#include <hip/hip_bf16.h>
#include <stdint.h>

typedef __bf16 bf16x8 __attribute__((ext_vector_type(8)));
typedef float f32x4 __attribute__((ext_vector_type(4)));
typedef unsigned short u16x4 __attribute__((ext_vector_type(4)));

__device__ __forceinline__ unsigned short f2bf(float f) {
    union { float f; uint32_t u; } v; v.f = f;
    uint32_t u = v.u;
    return (unsigned short)((u + 0x7fffu + ((u >> 16) & 1u)) >> 16);
}

__device__ __forceinline__ float bf2f(unsigned short b) {
    union { uint32_t u; float f; } v; v.u = ((uint32_t)b) << 16;
    return v.f;
}

// ---- prep: f32 -> bf16 feature conversion (x4); tail zeroes the pad row ----
__global__ __launch_bounds__(256) void prep_x(const f32x4* __restrict__ x,
                                              u16x4* __restrict__ xb, int n4, int n4tot) {
    int t = blockIdx.x * 256 + threadIdx.x;
    if (t < n4) {
        f32x4 v = x[t];
        u16x4 o;
        o.x = f2bf(v.x); o.y = f2bf(v.y); o.z = f2bf(v.z); o.w = f2bf(v.w);
        xb[t] = o;
    } else if (t < n4tot) {
        u16x4 z = {0, 0, 0, 0};
        xb[t] = z;                       // zero row at index N (masked-gather target)
    }
}

// ---- zero one 64-ch row (pad row of the hidden buffer) ----
__global__ void zero_row(unsigned short* __restrict__ p, long off) {
    p[off + threadIdx.x] = 0;
}

// ---- prep: W[k][ci][co] f32 -> FRAGMENT-ORDERED Wf[k][4096] bf16 ----
// u16 index = (ct*2+h)*512 + l*8 + j  <->  W[ci][co], ci = h*32+(l>>4)*8+j,
// co = ct*16+(l&15). LDS reads become lane-linear (base + lane*16B):
// bank-conflict-free, and staging is a plain linear copy.
__global__ __launch_bounds__(256) void prep_w(const float* __restrict__ W,
                                              unsigned short* __restrict__ Wf) {
    int k = blockIdx.x;
    unsigned short* Wfk = Wf + (size_t)k * 4096;
    const float* Wk = W + (size_t)k * 4096;
    for (int idx = threadIdx.x; idx < 4096; idx += 256) {
        int j   = idx & 7;
        int l   = (idx >> 3) & 63;
        int c2h = idx >> 9;               // ct*2 + h
        int ct  = c2h >> 1, h = c2h & 1;
        int ci  = h * 32 + (l >> 4) * 8 + j;
        int co  = ct * 16 + (l & 15);
        Wfk[idx] = f2bf(Wk[ci * 64 + co]);
    }
}

// ---- detect mask element width: 0=int32, 1=bytes(bool), 2=float32 ----
__global__ void detect_mask(const unsigned int* __restrict__ m, int* __restrict__ flag) {
    __shared__ int s_not_int, s_not_f32;
    if (threadIdx.x == 0) { s_not_int = 0; s_not_f32 = 0; }
    __syncthreads();
    unsigned int w = m[threadIdx.x];          // first 4KB: safe for all widths
    if (w > 1u) s_not_int = 1;                // benign race
    if (w != 0u && w != 0x3f800000u) s_not_f32 = 1;
    __syncthreads();
    if (threadIdx.x == 0) *flag = s_not_int ? (s_not_f32 ? 1 : 2) : 0;
}

// ---- asm 16B gather load (async; counted vmcnt domain) ----
template <int IOFF>
__device__ __forceinline__ bf16x8 gl16(const unsigned short* base, unsigned voff) {
    bf16x8 r;
    asm volatile("global_load_dwordx4 %0, %1, %2 offset:%c3"
                 : "=v"(r) : "v"(voff), "s"(base), "i"(IOFF));
    return r;
}

struct Slot { bf16x8 f[8]; };   // [at*2 + half]: 4 row-tiles x 2 k-halves

// counted wait tying the slot registers: consuming MFMAs can't be hoisted above.
template <int NW>
__device__ __forceinline__ void waitv(Slot& s) {
    asm volatile("s_waitcnt vmcnt(%c8)"
                 : "+v"(s.f[0]), "+v"(s.f[1]), "+v"(s.f[2]), "+v"(s.f[3]),
                   "+v"(s.f[4]), "+v"(s.f[5]), "+v"(s.f[6]), "+v"(s.f[7])
                 : "i"(NW));
    __builtin_amdgcn_sched_barrier(0);
}

__device__ __forceinline__ void gload_lds16(const unsigned short* g, unsigned short* l) {
    __builtin_amdgcn_global_load_lds(
        (const __attribute__((address_space(1))) void*)(const void*)g,
        (__attribute__((address_space(3))) void*)(void*)l, 16, 0, 0);
}

// ---- main sparse conv ----
// 4 waves x 64 rows = 256 rows/block, mfma 16x16x32, 4 row-tiles per wave.
// A gathered straight into fragments; W staged in LDS (fragment-ordered,
// lane-linear reads) double-buffered in 2-slice phases (32,768B LDS ->
// 4 blocks/CU). Counted vmcnt keeps gathers in flight. 27 real k-slices,
// no pad slice. All memory ops use default (cached) policy: the gather
// working set (xb/hb) must stay L2-resident.
// MODE 0: out = bf16 relu(acc + bias)   (hidden layer)
// MODE 1: out = f32  acc + bias + bf2f(residb) (final layer)
template <int MODE>
__global__ __launch_bounds__(256, 2) void conv_mfma(
    const unsigned short* __restrict__ xb,   // [N+1][64] bf16 (row N = zeros)
    const int* __restrict__ nbr,             // [N][K]
    const void* __restrict__ maskp,
    const int* __restrict__ flagp,
    const unsigned short* __restrict__ Wf,   // [27][4096] bf16 fragment-ordered
    const float* __restrict__ bias,          // [64]
    const unsigned short* __restrict__ residb, // [N][64] bf16 (MODE 1: = xb)
    void* __restrict__ outp,
    int N, int K)
{
    __shared__ unsigned short Wlds[16384];   // 2 bufs x 2 slices x 4096 = 32,768B

    const int tid = threadIdx.x;
    const int wv  = tid >> 6;
    const int l   = tid & 63;
    const int lr  = l & 15;          // fragment row/col
    const int lg  = l >> 4;          // k-chunk 0..3
    const int wavebase = blockIdx.x * 256 + wv * 64;

    // each lane owns exactly one row's neighbor offsets
    const int myrow = wavebase + l;
    const int mr = myrow < N ? myrow : N - 1;

    // ---- mask bits (uniform branch on detected dtype) ----
    unsigned mbits = 0;
    {
        const int flag = *flagp;
        long moff = (long)mr * K;
        if (flag == 1) {
            const unsigned char* mp = (const unsigned char*)maskp + moff;
#pragma unroll
            for (int k = 0; k < 27; ++k) mbits |= (mp[k] ? 1u : 0u) << k;
        } else if (flag == 0) {
            const int* mp = (const int*)maskp + moff;
#pragma unroll
            for (int k = 0; k < 27; ++k) mbits |= (mp[k] ? 1u : 0u) << k;
        } else {
            const float* mp = (const float*)maskp + moff;
#pragma unroll
            for (int k = 0; k < 27; ++k) mbits |= ((mp[k] != 0.f) ? 1u : 0u) << k;
        }
    }

    // ---- per-k byte offsets for my row (masked -> zero row N) ----
    unsigned o[27];
    {
        const int* nrow = nbr + (long)mr * K;
#pragma unroll
        for (int k = 0; k < 27; ++k) {
            unsigned g = ((mbits >> k) & 1u) ? (unsigned)nrow[k] : (unsigned)N;
            o[k] = g * 128u;
        }
    }

    // owner-lane bpermute addresses for the 4 row-tiles
    const int bpa0 = (0 * 16 + lr) * 4;
    const int bpa1 = (1 * 16 + lr) * 4;
    const int bpa2 = (2 * 16 + lr) * 4;
    const int bpa3 = (3 * 16 + lr) * 4;
    const unsigned chk = (unsigned)(lg << 4);    // chunk byte offset within 64B half

    f32x4 acc[4][4] = {};
    Slot pipe[2];
    bf16x8 Bf[8];

// stage 2 k-slices (16KB) for phase P into buffer P&1.
// dst is WAVE-UNIFORM (wv-based); src is per-lane (16B-contiguous).
#define STAGE(P) do { \
    const unsigned short* _src = Wf + (size_t)(P) * 8192 + wv * 2048 + (l << 3); \
    unsigned short* _dst = &Wlds[((P) & 1) * 8192 + wv * 2048]; \
    _Pragma("unroll") \
    for (int _s = 0; _s < 4; ++_s) \
        gload_lds16(_src + _s * 512, _dst + _s * 512); \
    asm volatile("" ::: "memory"); \
} while (0)

// stage ONE k-slice (8KB): first half of phase P's region
#define STAGE1(P) do { \
    const unsigned short* _src = Wf + (size_t)(P) * 8192 + wv * 1024 + (l << 3); \
    unsigned short* _dst = &Wlds[((P) & 1) * 8192 + wv * 1024]; \
    _Pragma("unroll") \
    for (int _s = 0; _s < 2; ++_s) \
        gload_lds16(_src + _s * 512, _dst + _s * 512); \
    asm volatile("" ::: "memory"); \
} while (0)

#define GISSUE(J) do { \
    unsigned _b0 = (unsigned)__builtin_amdgcn_ds_bpermute(bpa0, (int)o[J]) + chk; \
    unsigned _b1 = (unsigned)__builtin_amdgcn_ds_bpermute(bpa1, (int)o[J]) + chk; \
    unsigned _b2 = (unsigned)__builtin_amdgcn_ds_bpermute(bpa2, (int)o[J]) + chk; \
    unsigned _b3 = (unsigned)__builtin_amdgcn_ds_bpermute(bpa3, (int)o[J]) + chk; \
    Slot& _s = pipe[(J) & 1]; \
    _s.f[0] = gl16<0 >(xb, _b0); _s.f[1] = gl16<64>(xb, _b0); \
    _s.f[2] = gl16<0 >(xb, _b1); _s.f[3] = gl16<64>(xb, _b1); \
    _s.f[4] = gl16<0 >(xb, _b2); _s.f[5] = gl16<64>(xb, _b2); \
    _s.f[6] = gl16<0 >(xb, _b3); _s.f[7] = gl16<64>(xb, _b3); \
} while (0)

// lane-linear fragment read: buf=(J>>1)&1, slice=J&1; conflict-free
#define BLOAD(J) do { \
    const unsigned short* _wl = &Wlds[(((J) >> 1) & 1) * 8192 + ((J) & 1) * 4096]; \
    _Pragma("unroll") \
    for (int _c = 0; _c < 8; ++_c) \
        Bf[_c] = *(const bf16x8*)(_wl + _c * 512 + l * 8); \
} while (0)

#define MFMA16(J) do { \
    Slot& _s = pipe[(J) & 1]; \
    _Pragma("unroll") \
    for (int ct = 0; ct < 4; ++ct) { \
        _Pragma("unroll") \
        for (int at = 0; at < 4; ++at) { \
            acc[at][ct] = __builtin_amdgcn_mfma_f32_16x16x32_bf16(_s.f[at * 2],     Bf[ct * 2],     acc[at][ct], 0, 0, 0); \
            acc[at][ct] = __builtin_amdgcn_mfma_f32_16x16x32_bf16(_s.f[at * 2 + 1], Bf[ct * 2 + 1], acc[at][ct], 0, 0, 0); \
        } \
    } \
} while (0)

#define FENCE(NW) do { \
    asm volatile("s_waitcnt vmcnt(%c0)" :: "i"(NW) : "memory"); \
    __builtin_amdgcn_sched_barrier(0); \
    __builtin_amdgcn_s_barrier(); \
    __builtin_amdgcn_sched_barrier(0); \
} while (0)

#define STEP(J, NW) do { BLOAD(J); waitv<NW>(pipe[(J) & 1]); MFMA16(J); } while (0)

// one steady-state phase: stage next buffer, 2 compute steps, 2 gather issues
#define PHASE(PH1, K0) do { \
    STAGE(PH1); \
    STEP(K0, 12);       GISSUE((K0) + 2); \
    STEP((K0) + 1, 12); GISSUE((K0) + 3); \
    FENCE(16); \
} while (0)

    // ---- prologue: stage phase 0, start 2 gather sets ----
    STAGE(0);
    GISSUE(0); GISSUE(1);
    asm volatile("s_waitcnt vmcnt(16)" ::: "memory");   // STAGE(0) retired; G0,G1 fly
    __builtin_amdgcn_sched_barrier(0);
    __builtin_amdgcn_s_barrier();
    __builtin_amdgcn_sched_barrier(0);

    PHASE(1, 0);   PHASE(2, 2);   PHASE(3, 4);   PHASE(4, 6);
    PHASE(5, 8);   PHASE(6, 10);  PHASE(7, 12);  PHASE(8, 14);
    PHASE(9, 16);  PHASE(10, 18); PHASE(11, 20); PHASE(12, 22);
    // phase 13 (k 24,25; buf 1; stages only slice 26)
    STAGE1(13);
    STEP(24, 10); GISSUE(26);
    STEP(25, 10);
    FENCE(8);
    // tail (k 26; buf 1 slice 0)
    STEP(26, 0);

    // ---- epilogue: D col = ct*16 + lr, row = wavebase + at*16 + lg*4 + rg ----
#pragma unroll
    for (int at = 0; at < 4; ++at) {
#pragma unroll
        for (int ct = 0; ct < 4; ++ct) {
            int col = ct * 16 + lr;
            float bv = bias[col];
#pragma unroll
            for (int rg = 0; rg < 4; ++rg) {
                int row = wavebase + at * 16 + lg * 4 + rg;
                if (row < N) {
                    long oo = (long)row * 64 + col;
                    float v = acc[at][ct][rg] + bv;
                    if (MODE == 0) {
                        ((unsigned short*)outp)[oo] = f2bf(v > 0.f ? v : 0.f);
                    } else {
                        ((float*)outp)[oo] = v + bf2f(residb[oo]);
                    }
                }
            }
        }
    }

#undef STAGE
#undef STAGE1
#undef GISSUE
#undef BLOAD
#undef MFMA16
#undef FENCE
#undef STEP
#undef PHASE
}

static inline size_t align256(size_t x) { return (x + 255) & ~(size_t)255; }

extern "C" void kernel_launch(void* const* d_in, const int* in_sizes, int n_in,
                              void* d_out, int out_size, void* d_ws, size_t ws_size,
                              hipStream_t stream) {
    const float* x    = (const float*)d_in[0];
    const int*   nbr  = (const int*)d_in[1];
    const void*  mask = d_in[2];
    const float* W0   = (const float*)d_in[3];
    const float* b0   = (const float*)d_in[4];
    const float* W1   = (const float*)d_in[5];
    const float* b1   = (const float*)d_in[6];

    const int NC = in_sizes[0];      // N*64
    const int N  = NC / 64;
    const int K  = in_sizes[1] / N;  // 27

    char* ws = (char*)d_ws;
    size_t xb_bytes = (size_t)(NC + 64) * 2;   // +1 zero row
    size_t wt_bytes = (size_t)28 * 4096 * 2;   // fragment-ordered (27 used)
    size_t xb_off   = 0;
    size_t hb_off   = xb_off + align256(xb_bytes);
    size_t wt0_off  = hb_off + align256(xb_bytes);
    size_t wt1_off  = wt0_off + align256(wt_bytes);
    size_t flag_off = wt1_off + align256(wt_bytes);

    unsigned short* xb  = (unsigned short*)(ws + xb_off);
    unsigned short* hb  = (unsigned short*)(ws + hb_off);
    unsigned short* wf0 = (unsigned short*)(ws + wt0_off);
    unsigned short* wf1 = (unsigned short*)(ws + wt1_off);
    int* flag           = (int*)(ws + flag_off);

    int n4 = NC / 4;
    int n4tot = n4 + 16;             // + zero pad row (16 u16x4 = 64 ch)
    prep_x<<<(n4tot + 255) / 256, 256, 0, stream>>>((const f32x4*)x, (u16x4*)xb, n4, n4tot);
    zero_row<<<1, 64, 0, stream>>>(hb, (long)NC);
    prep_w<<<27, 256, 0, stream>>>(W0, wf0);
    prep_w<<<27, 256, 0, stream>>>(W1, wf1);
    detect_mask<<<1, 1024, 0, stream>>>((const unsigned int*)mask, flag);

    int nblocks = (N + 255) / 256;
    conv_mfma<0><<<nblocks, 256, 0, stream>>>(xb, nbr, mask, flag, wf0, b0, nullptr, hb, N, K);
    conv_mfma<1><<<nblocks, 256, 0, stream>>>(hb, nbr, mask, flag, wf1, b1, xb, d_out, N, K);
}

// Round 11
// 323.059 us; speedup vs baseline: 1.2900x; 1.0273x over previous
//
#include <hip/hip_runtime.h>
#include <hip/hip_bf16.h>
#include <stdint.h>

typedef __bf16 bf16x8 __attribute__((ext_vector_type(8)));
typedef float f32x4 __attribute__((ext_vector_type(4)));
typedef unsigned short u16x4 __attribute__((ext_vector_type(4)));

__device__ __forceinline__ unsigned short f2bf(float f) {
    union { float f; uint32_t u; } v; v.f = f;
    uint32_t u = v.u;
    return (unsigned short)((u + 0x7fffu + ((u >> 16) & 1u)) >> 16);
}

__device__ __forceinline__ float bf2f(unsigned short b) {
    union { uint32_t u; float f; } v; v.u = ((uint32_t)b) << 16;
    return v.f;
}

// ---- prep: f32 -> bf16 feature conversion (x4); tail zeroes the pad row ----
__global__ __launch_bounds__(256) void prep_x(const f32x4* __restrict__ x,
                                              u16x4* __restrict__ xb, int n4, int n4tot) {
    int t = blockIdx.x * 256 + threadIdx.x;
    if (t < n4) {
        f32x4 v = x[t];
        u16x4 o;
        o.x = f2bf(v.x); o.y = f2bf(v.y); o.z = f2bf(v.z); o.w = f2bf(v.w);
        xb[t] = o;
    } else if (t < n4tot) {
        u16x4 z = {0, 0, 0, 0};
        xb[t] = z;                       // zero row at index N (masked-gather target)
    }
}

// ---- zero one 64-ch row (pad row of the hidden buffer) ----
__global__ void zero_row(unsigned short* __restrict__ p, long off) {
    p[off + threadIdx.x] = 0;
}

// ---- prep: W[k][ci][co] f32 -> FRAGMENT-ORDERED Wf[k][4096] bf16 ----
// u16 index = (ct*2+h)*512 + l*8 + j  <->  W[ci][co], ci = h*32+(l>>4)*8+j,
// co = ct*16+(l&15). LDS reads become lane-linear (base + lane*16B):
// bank-conflict-free, and staging is a plain linear copy.
__global__ __launch_bounds__(256) void prep_w(const float* __restrict__ W,
                                              unsigned short* __restrict__ Wf) {
    int k = blockIdx.x;
    unsigned short* Wfk = Wf + (size_t)k * 4096;
    const float* Wk = W + (size_t)k * 4096;
    for (int idx = threadIdx.x; idx < 4096; idx += 256) {
        int j   = idx & 7;
        int l   = (idx >> 3) & 63;
        int c2h = idx >> 9;               // ct*2 + h
        int ct  = c2h >> 1, h = c2h & 1;
        int ci  = h * 32 + (l >> 4) * 8 + j;
        int co  = ct * 16 + (l & 15);
        Wfk[idx] = f2bf(Wk[ci * 64 + co]);
    }
}

// ---- detect mask element width: 0=int32, 1=bytes(bool), 2=float32 ----
__global__ void detect_mask(const unsigned int* __restrict__ m, int* __restrict__ flag) {
    __shared__ int s_not_int, s_not_f32;
    if (threadIdx.x == 0) { s_not_int = 0; s_not_f32 = 0; }
    __syncthreads();
    unsigned int w = m[threadIdx.x];          // first 4KB: safe for all widths
    if (w > 1u) s_not_int = 1;                // benign race
    if (w != 0u && w != 0x3f800000u) s_not_f32 = 1;
    __syncthreads();
    if (threadIdx.x == 0) *flag = s_not_int ? (s_not_f32 ? 1 : 2) : 0;
}

// ---- asm 16B gather load (async; counted vmcnt domain) ----
template <int IOFF>
__device__ __forceinline__ bf16x8 gl16(const unsigned short* base, unsigned voff) {
    bf16x8 r;
    asm volatile("global_load_dwordx4 %0, %1, %2 offset:%c3"
                 : "=v"(r) : "v"(voff), "s"(base), "i"(IOFF));
    return r;
}

struct Slot { bf16x8 f[4]; };   // [at*2 + half]: 2 row-tiles x 2 k-halves

// counted wait tying the slot registers: consuming MFMAs can't be hoisted above.
template <int NW>
__device__ __forceinline__ void waitv(Slot& s) {
    asm volatile("s_waitcnt vmcnt(%c4)"
                 : "+v"(s.f[0]), "+v"(s.f[1]), "+v"(s.f[2]), "+v"(s.f[3])
                 : "i"(NW));
    __builtin_amdgcn_sched_barrier(0);
}

__device__ __forceinline__ void gload_lds16(const unsigned short* g, unsigned short* l) {
    __builtin_amdgcn_global_load_lds(
        (const __attribute__((address_space(1))) void*)(const void*)g,
        (__attribute__((address_space(3))) void*)(void*)l, 16, 0, 0);
}

// ---- main sparse conv ----
// 4 waves x 32 rows = 128 rows/block, mfma 16x16x32, 2 row-tiles per wave.
// Register budget engineered for 4 waves/SIMD residency (<=128 VGPR+AGPR):
// acc 32 AGPR + pipe 32 + Bf 16 + o[27] + misc ~ 123. LDS 32,768B (4 blocks).
// This is the true 2x-TLP experiment (all prior rounds ran 2 blocks/CU).
// MODE 0: out = bf16 relu(acc + bias)   (hidden layer)
// MODE 1: out = f32  acc + bias + bf2f(residb) (final layer)
template <int MODE>
__global__ __launch_bounds__(256, 4) void conv_mfma(
    const unsigned short* __restrict__ xb,   // [N+1][64] bf16 (row N = zeros)
    const int* __restrict__ nbr,             // [N][K]
    const void* __restrict__ maskp,
    const int* __restrict__ flagp,
    const unsigned short* __restrict__ Wf,   // [27][4096] bf16 fragment-ordered
    const float* __restrict__ bias,          // [64]
    const unsigned short* __restrict__ residb, // [N][64] bf16 (MODE 1: = xb)
    void* __restrict__ outp,
    int N, int K)
{
    __shared__ unsigned short Wlds[16384];   // 2 bufs x 2 slices x 4096 = 32,768B

    const int tid = threadIdx.x;
    const int wv  = tid >> 6;
    const int l   = tid & 63;
    const int lr  = l & 15;          // fragment row/col
    const int lg  = l >> 4;          // k-chunk 0..3
    const int wavebase = blockIdx.x * 128 + wv * 32;

    // lanes 0..31 own rows; lanes 32..63 duplicate (bpermute sources 0..31)
    const int myrow = wavebase + (l & 31);
    const int mr = myrow < N ? myrow : N - 1;

    // ---- mask bits (uniform branch on detected dtype) ----
    unsigned mbits = 0;
    {
        const int flag = *flagp;
        long moff = (long)mr * K;
        if (flag == 1) {
            const unsigned char* mp = (const unsigned char*)maskp + moff;
#pragma unroll
            for (int k = 0; k < 27; ++k) mbits |= (mp[k] ? 1u : 0u) << k;
        } else if (flag == 0) {
            const int* mp = (const int*)maskp + moff;
#pragma unroll
            for (int k = 0; k < 27; ++k) mbits |= (mp[k] ? 1u : 0u) << k;
        } else {
            const float* mp = (const float*)maskp + moff;
#pragma unroll
            for (int k = 0; k < 27; ++k) mbits |= ((mp[k] != 0.f) ? 1u : 0u) << k;
        }
    }

    // ---- per-k byte offsets for my row (masked -> zero row N) ----
    unsigned o[27];
    {
        const int* nrow = nbr + (long)mr * K;
#pragma unroll
        for (int k = 0; k < 27; ++k) {
            unsigned g = ((mbits >> k) & 1u) ? (unsigned)nrow[k] : (unsigned)N;
            o[k] = g * 128u;
        }
    }

    // owner-lane bpermute addresses for the 2 row-tiles
    const int bpa0 = (0 * 16 + lr) * 4;
    const int bpa1 = (1 * 16 + lr) * 4;
    const unsigned chk = (unsigned)(lg << 4);    // chunk byte offset within 64B half

    f32x4 acc[2][4] = {};
    Slot pipe[2];
    bf16x8 Bf[4];

// stage 2 k-slices (16KB) for phase P into buffer P&1.
// dst is WAVE-UNIFORM (wv-based); src is per-lane (16B-contiguous).
#define STAGE(P) do { \
    const unsigned short* _src = Wf + (size_t)(P) * 8192 + wv * 2048 + (l << 3); \
    unsigned short* _dst = &Wlds[((P) & 1) * 8192 + wv * 2048]; \
    _Pragma("unroll") \
    for (int _s = 0; _s < 4; ++_s) \
        gload_lds16(_src + _s * 512, _dst + _s * 512); \
    asm volatile("" ::: "memory"); \
} while (0)

// stage ONE k-slice (8KB): first half of phase P's region
#define STAGE1(P) do { \
    const unsigned short* _src = Wf + (size_t)(P) * 8192 + wv * 1024 + (l << 3); \
    unsigned short* _dst = &Wlds[((P) & 1) * 8192 + wv * 1024]; \
    _Pragma("unroll") \
    for (int _s = 0; _s < 2; ++_s) \
        gload_lds16(_src + _s * 512, _dst + _s * 512); \
    asm volatile("" ::: "memory"); \
} while (0)

#define GISSUE(J) do { \
    unsigned _b0 = (unsigned)__builtin_amdgcn_ds_bpermute(bpa0, (int)o[J]) + chk; \
    unsigned _b1 = (unsigned)__builtin_amdgcn_ds_bpermute(bpa1, (int)o[J]) + chk; \
    Slot& _s = pipe[(J) & 1]; \
    _s.f[0] = gl16<0 >(xb, _b0); _s.f[1] = gl16<64>(xb, _b0); \
    _s.f[2] = gl16<0 >(xb, _b1); _s.f[3] = gl16<64>(xb, _b1); \
} while (0)

// lane-linear fragment read of 4 B-frags for ct-pair CP (0: ct0,1; 1: ct2,3)
#define BLOADH(J, CP) do { \
    const unsigned short* _wl = &Wlds[(((J) >> 1) & 1) * 8192 + ((J) & 1) * 4096]; \
    _Pragma("unroll") \
    for (int _c = 0; _c < 4; ++_c) \
        Bf[_c] = *(const bf16x8*)(_wl + ((CP) * 4 + _c) * 512 + l * 8); \
} while (0)

// 8 MFMAs for ct-pair CP using current Bf
#define MFMA8(J, CP) do { \
    Slot& _s = pipe[(J) & 1]; \
    _Pragma("unroll") \
    for (int _q = 0; _q < 2; ++_q) { \
        int ct = (CP) * 2 + _q; \
        _Pragma("unroll") \
        for (int at = 0; at < 2; ++at) { \
            acc[at][ct] = __builtin_amdgcn_mfma_f32_16x16x32_bf16(_s.f[at * 2],     Bf[_q * 2],     acc[at][ct], 0, 0, 0); \
            acc[at][ct] = __builtin_amdgcn_mfma_f32_16x16x32_bf16(_s.f[at * 2 + 1], Bf[_q * 2 + 1], acc[at][ct], 0, 0, 0); \
        } \
    } \
} while (0)

#define FENCE(NW) do { \
    asm volatile("s_waitcnt vmcnt(%c0)" :: "i"(NW) : "memory"); \
    __builtin_amdgcn_sched_barrier(0); \
    __builtin_amdgcn_s_barrier(); \
    __builtin_amdgcn_sched_barrier(0); \
} while (0)

#define STEP(J, NW) do { \
    BLOADH(J, 0); waitv<NW>(pipe[(J) & 1]); MFMA8(J, 0); \
    BLOADH(J, 1); MFMA8(J, 1); \
} while (0)

// one steady-state phase: stage next buffer, 2 compute steps, 2 gather issues
#define PHASE(PH1, K0) do { \
    STAGE(PH1); \
    STEP(K0, 8);       GISSUE((K0) + 2); \
    STEP((K0) + 1, 8); GISSUE((K0) + 3); \
    FENCE(8); \
} while (0)

    // ---- prologue: stage phase 0, start 2 gather sets ----
    STAGE(0);
    GISSUE(0); GISSUE(1);
    asm volatile("s_waitcnt vmcnt(8)" ::: "memory");   // STAGE(0) retired; G0,G1 fly
    __builtin_amdgcn_sched_barrier(0);
    __builtin_amdgcn_s_barrier();
    __builtin_amdgcn_sched_barrier(0);

    PHASE(1, 0);   PHASE(2, 2);   PHASE(3, 4);   PHASE(4, 6);
    PHASE(5, 8);   PHASE(6, 10);  PHASE(7, 12);  PHASE(8, 14);
    PHASE(9, 16);  PHASE(10, 18); PHASE(11, 20); PHASE(12, 22);
    // phase 13 (k 24,25; buf 0; stages only slice 26 into buf 1)
    STAGE1(13);
    STEP(24, 6); GISSUE(26);
    STEP(25, 6);
    FENCE(4);
    // tail (k 26; buf 1 slice 0)
    STEP(26, 0);

    // ---- epilogue: D col = ct*16 + lr, row = wavebase + at*16 + lg*4 + rg ----
#pragma unroll
    for (int at = 0; at < 2; ++at) {
#pragma unroll
        for (int ct = 0; ct < 4; ++ct) {
            int col = ct * 16 + lr;
            float bv = bias[col];
#pragma unroll
            for (int rg = 0; rg < 4; ++rg) {
                int row = wavebase + at * 16 + lg * 4 + rg;
                if (row < N) {
                    long oo = (long)row * 64 + col;
                    float v = acc[at][ct][rg] + bv;
                    if (MODE == 0) {
                        ((unsigned short*)outp)[oo] = f2bf(v > 0.f ? v : 0.f);
                    } else {
                        ((float*)outp)[oo] = v + bf2f(residb[oo]);
                    }
                }
            }
        }
    }

#undef STAGE
#undef STAGE1
#undef GISSUE
#undef BLOADH
#undef MFMA8
#undef FENCE
#undef STEP
#undef PHASE
}

static inline size_t align256(size_t x) { return (x + 255) & ~(size_t)255; }

extern "C" void kernel_launch(void* const* d_in, const int* in_sizes, int n_in,
                              void* d_out, int out_size, void* d_ws, size_t ws_size,
                              hipStream_t stream) {
    const float* x    = (const float*)d_in[0];
    const int*   nbr  = (const int*)d_in[1];
    const void*  mask = d_in[2];
    const float* W0   = (const float*)d_in[3];
    const float* b0   = (const float*)d_in[4];
    const float* W1   = (const float*)d_in[5];
    const float* b1   = (const float*)d_in[6];

    const int NC = in_sizes[0];      // N*64
    const int N  = NC / 64;
    const int K  = in_sizes[1] / N;  // 27

    char* ws = (char*)d_ws;
    size_t xb_bytes = (size_t)(NC + 64) * 2;   // +1 zero row
    size_t wt_bytes = (size_t)28 * 4096 * 2;   // fragment-ordered (27 used)
    size_t xb_off   = 0;
    size_t hb_off   = xb_off + align256(xb_bytes);
    size_t wt0_off  = hb_off + align256(xb_bytes);
    size_t wt1_off  = wt0_off + align256(wt_bytes);
    size_t flag_off = wt1_off + align256(wt_bytes);

    unsigned short* xb  = (unsigned short*)(ws + xb_off);
    unsigned short* hb  = (unsigned short*)(ws + hb_off);
    unsigned short* wf0 = (unsigned short*)(ws + wt0_off);
    unsigned short* wf1 = (unsigned short*)(ws + wt1_off);
    int* flag           = (int*)(ws + flag_off);

    int n4 = NC / 4;
    int n4tot = n4 + 16;             // + zero pad row (16 u16x4 = 64 ch)
    prep_x<<<(n4tot + 255) / 256, 256, 0, stream>>>((const f32x4*)x, (u16x4*)xb, n4, n4tot);
    zero_row<<<1, 64, 0, stream>>>(hb, (long)NC);
    prep_w<<<27, 256, 0, stream>>>(W0, wf0);
    prep_w<<<27, 256, 0, stream>>>(W1, wf1);
    detect_mask<<<1, 1024, 0, stream>>>((const unsigned int*)mask, flag);

    int nblocks = (N + 127) / 128;
    conv_mfma<0><<<nblocks, 256, 0, stream>>>(xb, nbr, mask, flag, wf0, b0, nullptr, hb, N, K);
    conv_mfma<1><<<nblocks, 256, 0, stream>>>(hb, nbr, mask, flag, wf1, b1, xb, d_out, N, K);
}